// Round 4
// baseline (102.425 us; speedup 1.0000x reference)
//
#include <hip/hip_runtime.h>

// PrRoIPool2D(16,16) over full 32x32 box == fixed separable 4-tap resize.
// N=128, C=512, H1=W1=32 -> 16x16. Wave-private version: 8192 waves, each
// owns 8 contiguous planes; one wave does a whole plane (load 4KB -> private
// LDS -> 4 outputs/lane -> one float4 NT store). ZERO barriers: single-wave
// DS ordering makes the private buffer WAR-safe. Depth-1 register prefetch.
#define H1 32
#define W1 32
#define NPLANES (128 * 512)
#define NBLK 2048
#define WPB 4                            // waves per block
#define PPW (NPLANES / (NBLK * WPB))     // 8 planes per wave
#define LDS_STRIDE 36                    // 144B rows: aligned b128 writes, <=4-way reads

typedef float f32x4v __attribute__((ext_vector_type(4)));

__device__ __forceinline__ float tri_G(float t) {
    // antiderivative of max(0, 1-|t|), clamped to support
    t = fminf(1.0f, fmaxf(-1.0f, t));
    return (t <= 0.0f) ? 0.5f * (t + 1.0f) * (t + 1.0f)
                       : 0.5f + t - 0.5f * t * t;
}

__global__ __launch_bounds__(256, 8) void prroi_resize_kernel(
    const float* __restrict__ in, float* __restrict__ out) {
    __shared__ float xs[WPB][H1 * LDS_STRIDE];

    const int t = threadIdx.x;
    const int w = t >> 6;  // wave within block (private LDS slab)
    const int l = t & 63;  // lane
    const int p0 = (blockIdx.x * WPB + w) * PPW;  // first plane of this wave

    // ---- staging base: granule g = q*64+l -> row q*8+(l>>3), colgrp l&7 ----
    float* const stb = &xs[w][(l >> 3) * LDS_STRIDE + ((l & 7) << 2)];

    // ---- per-lane outputs: row i, cols j0..j0+3 (whole plane per wave) ----
    const int i = l >> 2;
    const int j0 = (l & 3) << 2;

    const float binsz = 31.0f / 16.0f;
    const float inv_area = 1.0f / (binsz * binsz);
    const float ey0 = i * binsz, ey1 = ey0 + binsz;
    int h0 = (int)floorf(ey0 - 1.0f) + 1;
    h0 = max(0, min(h0, H1 - 4));
    float wy[4];
#pragma unroll
    for (int k = 0; k < 4; ++k) {
        const float p = (float)(h0 + k);
        wy[k] = (tri_G(ey1 - p) - tri_G(ey0 - p)) * inv_area;  // fold 1/area
    }

    float wx[4][4];
    const float* rp[4];  // per-jj LDS read base (all later indices static)
#pragma unroll
    for (int jj = 0; jj < 4; ++jj) {
        const float ex0 = (j0 + jj) * binsz, ex1 = ex0 + binsz;
        int w0 = (int)floorf(ex0 - 1.0f) + 1;
        w0 = max(0, min(w0, W1 - 4));
#pragma unroll
        for (int m = 0; m < 4; ++m) {
            const float p = (float)(w0 + m);
            wx[jj][m] = tri_G(ex1 - p) - tri_G(ex0 - p);
        }
        rp[jj] = &xs[w][h0 * LDS_STRIDE + w0];
    }

    // ---- streams ----
    const float4* src = reinterpret_cast<const float4*>(in) + (size_t)p0 * 256 + l;
    float4* dst = reinterpret_cast<float4*>(out) + (size_t)p0 * 64 + i * 4 + (l & 3);

    // depth-1 prefetch prologue: plane p0 in flight
    float4 v0 = src[0], v1 = src[64], v2 = src[128], v3 = src[192];
    src += 256;

#pragma unroll
    for (int p = 0; p < PPW; ++p) {
        // stage plane p (compiler-counted vmcnt waits on v0..v3)
        *reinterpret_cast<float4*>(stb) = v0;
        *reinterpret_cast<float4*>(stb + 8 * LDS_STRIDE) = v1;
        *reinterpret_cast<float4*>(stb + 16 * LDS_STRIDE) = v2;
        *reinterpret_cast<float4*>(stb + 24 * LDS_STRIDE) = v3;
        if (p + 1 < PPW) {  // issue next plane now; lands during compute
            v0 = src[0]; v1 = src[64]; v2 = src[128]; v3 = src[192];
            src += 256;
        }

        // same-wave DS pipe is in-order: reads below see the writes above,
        // and next iteration's writes can't pass these reads. No syncs.
        float a0 = 0.f, a1 = 0.f, a2 = 0.f, a3 = 0.f;
#pragma unroll
        for (int k = 0; k < 4; ++k) {
            const int ro = k * LDS_STRIDE;
            a0 = fmaf(wy[k],
                      rp[0][ro] * wx[0][0] + rp[0][ro + 1] * wx[0][1] +
                      rp[0][ro + 2] * wx[0][2] + rp[0][ro + 3] * wx[0][3], a0);
            a1 = fmaf(wy[k],
                      rp[1][ro] * wx[1][0] + rp[1][ro + 1] * wx[1][1] +
                      rp[1][ro + 2] * wx[1][2] + rp[1][ro + 3] * wx[1][3], a1);
            a2 = fmaf(wy[k],
                      rp[2][ro] * wx[2][0] + rp[2][ro + 1] * wx[2][1] +
                      rp[2][ro + 2] * wx[2][2] + rp[2][ro + 3] * wx[2][3], a2);
            a3 = fmaf(wy[k],
                      rp[3][ro] * wx[3][0] + rp[3][ro + 1] * wx[3][1] +
                      rp[3][ro + 2] * wx[3][2] + rp[3][ro + 3] * wx[3][3], a3);
        }

        f32x4v res = {a0, a1, a2, a3};  // one coalesced 1KB store per wave
        __builtin_nontemporal_store(res, reinterpret_cast<f32x4v*>(dst));
        dst += 64;
    }
}

extern "C" void kernel_launch(void* const* d_in, const int* in_sizes, int n_in,
                              void* d_out, int out_size, void* d_ws,
                              size_t ws_size, hipStream_t stream) {
    const float* in = (const float*)d_in[0];
    float* out = (float*)d_out;
    prroi_resize_kernel<<<NBLK, WPB * 64, 0, stream>>>(in, out);
}

// Round 6
// 66.027 us; speedup vs baseline: 1.5513x; 1.5513x over previous
//
#include <hip/hip_runtime.h>

// PrRoIPool2D(16,16) over full 32x32 box == fixed separable 4-tap resize.
// N=128, C=512. Wave-private: each wave owns 8 planes; per plane: 4 dwordx4
// loads -> private LDS slab -> 4 outputs/lane (shared 10-float row reads)
// -> one dwordx4 store. No barriers in the loop (same-wave DS ordering).
// Uniform tap window h0'(i)=2i-1 / w0'(j)=2j-1: edge taps have weight==0
// (pads zeroed once so 0-weight never multiplies garbage/NaN).
// R4 lesson: launch_bounds(256,8) forced VGPR<=64 -> spills. Use (256,4).
// (R5 was an infrastructure failure — same kernel resubmitted.)
#define H1 32
#define W1 32
#define NPLANES (128 * 512)
#define NBLK 2048
#define WPB 4                          // waves per block
#define PPW (NPLANES / (NBLK * WPB))   // 8 planes per wave
#define RSTRIDE 36                     // floats per LDS row (144B, b128-aligned)
#define SLAB (H1 * RSTRIDE)            // 1152 floats per wave slab

typedef float f32x4 __attribute__((ext_vector_type(4)));

__device__ __forceinline__ float tri_G(float t) {
    // antiderivative of max(0, 1-|t|), clamped to support
    t = fminf(1.0f, fmaxf(-1.0f, t));
    return (t <= 0.0f) ? 0.5f * (t + 1.0f) * (t + 1.0f)
                       : 0.5f + t - 0.5f * t * t;
}

__global__ __launch_bounds__(256, 4) void prroi_resize_kernel(
    const float* __restrict__ in, float* __restrict__ out) {
    // +4 front pad: col -1 of row 0 / wave 0 stays in-bounds (and zero)
    __shared__ float xs[4 + WPB * SLAB];

    const int t = threadIdx.x;
    const int w = t >> 6;  // wave index -> private slab, private planes
    const int l = t & 63;
    float* const slab = &xs[4 + w * SLAB];

    // one-time zero so pad cols / 0-weight taps read 0.0 (never stale NaN)
#pragma unroll
    for (int q = 0; q < SLAB / 64; ++q) slab[q * 64 + l] = 0.0f;
    if (t < 4) xs[t] = 0.0f;
    __syncthreads();  // once; cross-wave pad visibility (never in the loop)

    // ---- per-lane geometry: 4 outputs (i, 4g..4g+3) of own plane ----
    const int i = l >> 2;
    const int g = l & 3;

    const float binsz = 31.0f / 16.0f;
    const float inv_area = 1.0f / (binsz * binsz);
    const float ey0 = i * binsz, ey1 = ey0 + binsz;
    float wy[4];
#pragma unroll
    for (int k = 0; k < 4; ++k) {  // taps p = 2i-1+k; edge taps -> weight 0
        const float p = (float)(2 * i - 1 + k);
        wy[k] = (tri_G(ey1 - p) - tri_G(ey0 - p)) * inv_area;
    }
    float wx[4][4];
#pragma unroll
    for (int jj = 0; jj < 4; ++jj) {
        const int j = 4 * g + jj;
        const float ex0 = j * binsz, ex1 = ex0 + binsz;
#pragma unroll
        for (int m = 0; m < 4; ++m) {
            const float p = (float)(2 * j - 1 + m);
            wx[jj][m] = tri_G(ex1 - p) - tri_G(ex0 - p);
        }
    }
    // row read bases: row 2i-1+k clamped (clamped rows pair with 0 weights),
    // col base 8g-1 (g==0 hits the zeroed pad at base-1)
    const float* rb[4];
#pragma unroll
    for (int k = 0; k < 4; ++k) {
        const int r = min(max(2 * i - 1 + k, 0), H1 - 1);
        rb[k] = slab + r * RSTRIDE + 8 * g - 1;
    }
    // staging: granule q*64+l -> row q*8+(l>>3), cols (l&7)*4 (16B aligned)
    float* const stb = slab + (l >> 3) * RSTRIDE + ((l & 7) << 2);

    // ---- streams ----
    const int p0 = (blockIdx.x * WPB + w) * PPW;
    const f32x4* src = reinterpret_cast<const f32x4*>(in) + (size_t)p0 * 256 + l;
    f32x4* dst = reinterpret_cast<f32x4*>(out) + (size_t)p0 * 64 + l;

    // depth-1 prefetch prologue
    f32x4 v0 = src[0], v1 = src[64], v2 = src[128], v3 = src[192];
    src += 256;

#pragma unroll 2
    for (int p = 0; p < PPW; ++p) {
        // stage plane p (compiler-counted vmcnt waits per v)
        *reinterpret_cast<f32x4*>(stb) = v0;
        *reinterpret_cast<f32x4*>(stb + 8 * RSTRIDE) = v1;
        *reinterpret_cast<f32x4*>(stb + 16 * RSTRIDE) = v2;
        *reinterpret_cast<f32x4*>(stb + 24 * RSTRIDE) = v3;
        if (p + 1 < PPW) {  // issue next plane; lands during compute
            v0 = src[0]; v1 = src[64]; v2 = src[128]; v3 = src[192];
            src += 256;
        }

        // same-wave DS pipe is in-order: no sync needed, single buffer safe
        float a0 = 0.f, a1 = 0.f, a2 = 0.f, a3 = 0.f;
#pragma unroll
        for (int k = 0; k < 4; ++k) {
            const float* r = rb[k];
            const float c0 = r[0], c1 = r[1], c2 = r[2], c3 = r[3], c4 = r[4];
            const float c5 = r[5], c6 = r[6], c7 = r[7], c8 = r[8], c9 = r[9];
            a0 = fmaf(wy[k], c0*wx[0][0] + c1*wx[0][1] + c2*wx[0][2] + c3*wx[0][3], a0);
            a1 = fmaf(wy[k], c2*wx[1][0] + c3*wx[1][1] + c4*wx[1][2] + c5*wx[1][3], a1);
            a2 = fmaf(wy[k], c4*wx[2][0] + c5*wx[2][1] + c6*wx[2][2] + c7*wx[2][3], a2);
            a3 = fmaf(wy[k], c6*wx[3][0] + c7*wx[3][1] + c8*wx[3][2] + c9*wx[3][3], a3);
        }

        f32x4 res = {a0, a1, a2, a3};  // one coalesced 1KB store per wave
        dst[0] = res;
        dst += 64;
    }
}

extern "C" void kernel_launch(void* const* d_in, const int* in_sizes, int n_in,
                              void* d_out, int out_size, void* d_ws,
                              size_t ws_size, hipStream_t stream) {
    const float* in = (const float*)d_in[0];
    float* out = (float*)d_out;
    prroi_resize_kernel<<<NBLK, WPB * 64, 0, stream>>>(in, out);
}